// Round 8
// baseline (513.401 us; speedup 1.0000x reference)
//
#include <hip/hip_runtime.h>
#include <math.h>

#define HID 128
#define G3  384
#define BATCH 256
#define SEQ 512
#define NB 16            // batch tile per scan block
#define NBLK (BATCH/NB)  // 16 scan blocks

typedef __bf16 bf16x8 __attribute__((ext_vector_type(8)));
typedef __bf16 bf16x4 __attribute__((ext_vector_type(4)));
typedef float  f32x4  __attribute__((ext_vector_type(4)));

#define LOG2E 1.44269504088896f

__device__ __forceinline__ float sigm(float x) {
    return __builtin_amdgcn_rcpf(1.f + __builtin_amdgcn_exp2f(-LOG2E * x));
}
__device__ __forceinline__ float tanh_fast(float x) {
    float e = __builtin_amdgcn_exp2f(-2.f * LOG2E * x);
    return __builtin_amdgcn_rcpf(1.f + e) * 2.f - 1.f;
}
__device__ __forceinline__ f32x4 mfma16(bf16x8 a, bf16x8 b, f32x4 c) {
    return __builtin_amdgcn_mfma_f32_16x16x32_bf16(a, b, c, 0, 0, 0);
}
__device__ __forceinline__ bf16x8 cvt8(float4 a, float4 b) {
    bf16x8 f;
    f[0] = (__bf16)a.x; f[1] = (__bf16)a.y; f[2] = (__bf16)a.z; f[3] = (__bf16)a.w;
    f[4] = (__bf16)b.x; f[5] = (__bf16)b.y; f[6] = (__bf16)b.z; f[7] = (__bf16)b.w;
    return f;
}
__device__ __forceinline__ bf16x4 cvt4(float4 a) {
    bf16x4 f;
    f[0] = (__bf16)a.x; f[1] = (__bf16)a.y; f[2] = (__bf16)a.z; f[3] = (__bf16)a.w;
    return f;
}
__device__ __forceinline__ float bflo(unsigned u) { return __uint_as_float(u << 16); }
__device__ __forceinline__ float bfhi(unsigned u) { return __uint_as_float(u & 0xffff0000u); }

// ===========================================================================
// FAST PATH (needs ws_size >= ~100.8 MB)
// ===========================================================================

// ---- fold: Wc = W_ih @ lin_W (bf16 out), bcA = W_ih @ lin_b + b_ih -------
__global__ void fold_bf16_kernel(const float* __restrict__ lin_W,
                                 const float* __restrict__ lin_b,
                                 const float* __restrict__ W_ih,
                                 const float* __restrict__ b_ih,
                                 __bf16* __restrict__ Wcbf,
                                 float* __restrict__ bcA) {
    const int g = blockIdx.x;
    const int d = threadIdx.x;
    float acc = 0.f;
    for (int e = 0; e < HID; ++e) acc += W_ih[g * HID + e] * lin_W[e * HID + d];
    Wcbf[g * HID + d] = (__bf16)acc;
    if (d == 0) {
        float b = 0.f;
        for (int e = 0; e < HID; ++e) b += W_ih[g * HID + e] * lin_b[e];
        bcA[g] = b + b_ih[g];
    }
}

// ---- gx GEMM: gx[m][g] = bf16( Wc[g,:] . X[m,:] + bcA[g] ), m = s*B+b ----
// 1024 blocks x 512 thr (8 waves). Block: 128 m-rows; wave w: rows w*16+col.
// No LDS, no barriers: A-frags read from L2-hot Wcbf per g-tile.
__global__ __launch_bounds__(512, 2)
void gemm_gx_kernel(const float* __restrict__ X,
                    const __bf16* __restrict__ Wcbf,
                    const float* __restrict__ bcA,
                    __bf16* __restrict__ gx) {
    const int t   = threadIdx.x;
    const int w   = t >> 6;
    const int l   = t & 63;
    const int col = l & 15;
    const int lr  = l >> 4;
    const int m   = blockIdx.x * 128 + w * 16 + col;

    // B-frags: this lane's X row slice (row=col within wave tile)
    bf16x8 Bx[4];
    const float* px = X + (size_t)m * HID + lr * 8;
    #pragma unroll
    for (int kt = 0; kt < 4; ++kt)
        Bx[kt] = cvt8(*(const float4*)(px + kt * 32), *(const float4*)(px + kt * 32 + 4));

    #pragma unroll 4
    for (int gt = 0; gt < 24; ++gt) {
        const int g0 = gt * 16;
        const __bf16* pa = Wcbf + (size_t)(g0 + col) * HID + lr * 8;
        bf16x8 A0 = *(const bf16x8*)(pa);
        bf16x8 A1 = *(const bf16x8*)(pa + 32);
        bf16x8 A2 = *(const bf16x8*)(pa + 64);
        bf16x8 A3 = *(const bf16x8*)(pa + 96);
        float4 bc4 = *(const float4*)(bcA + g0 + lr * 4);
        f32x4 acc; acc[0] = bc4.x; acc[1] = bc4.y; acc[2] = bc4.z; acc[3] = bc4.w;
        acc = mfma16(A0, Bx[0], acc);
        acc = mfma16(A1, Bx[1], acc);
        acc = mfma16(A2, Bx[2], acc);
        acc = mfma16(A3, Bx[3], acc);
        float4 o; o.x = acc[0]; o.y = acc[1]; o.z = acc[2]; o.w = acc[3];
        *(bf16x4*)(gx + (size_t)m * G3 + g0 + lr * 4) = cvt4(o);
    }
}

// ---- light scan: gh = W_hh @ h only (12 MFMA/wave); gx read from global --
__global__ __launch_bounds__(512, 2)
void gru_scan_light(const float* __restrict__ h0,
                    const float* __restrict__ W_hh,
                    const float* __restrict__ b_hh,
                    const __bf16* __restrict__ gx,
                    float* __restrict__ out) {
    const int t   = threadIdx.x;
    const int w   = t >> 6;     // 0..7: row tile
    const int l   = t & 63;
    const int col = l & 15;     // batch within tile
    const int lr  = l >> 4;     // 0..3
    const int bb  = blockIdx.x * NB;

    __shared__ __align__(16) unsigned char lds[8192];
    unsigned char* hA = lds;          // h buffer, even-step read
    unsigned char* hB = lds + 4096;   // h buffer, odd-step read

    auto SW = [](int b, int off) { return b * 256 + (off ^ ((b & 7) << 4)); };

    // ---- resident A-fragments of W_hh only: [gate][ktile] ---------------
    bf16x8 aW[3][4];
    #pragma unroll
    for (int g3 = 0; g3 < 3; ++g3)
        #pragma unroll
        for (int kt = 0; kt < 4; ++kt) {
            const int row = g3 * HID + w * 16 + col;
            const float* pw = W_hh + row * HID + kt * 32 + lr * 8;
            aW[g3][kt] = cvt8(*(const float4*)pw, *(const float4*)(pw + 4));
        }
    #pragma unroll
    for (int g3 = 0; g3 < 3; ++g3)
        #pragma unroll
        for (int kt = 0; kt < 4; ++kt)
            asm volatile("" : "+v"(aW[g3][kt]));

    // ---- b_hh as accumulator initializers -------------------------------
    f32x4 vbr, vbz, vbnh;
    #pragma unroll
    for (int q = 0; q < 4; ++q) {
        const int g = w * 16 + lr * 4 + q;
        vbr[q]  = b_hh[g];
        vbz[q]  = b_hh[HID + g];
        vbnh[q] = b_hh[2 * HID + g];
    }

    // ---- h_old rows this lane owns --------------------------------------
    f32x4 hold = *(const f32x4*)(h0 + (size_t)(bb + col) * HID + w * 16 + lr * 4);

    // ---- per-lane gx addressing: row m = s*BATCH + bb + col -------------
    const size_t gxoff = (size_t)(bb + col) * G3 + w * 16 + lr * 4;

    // prime: h0 -> hA, gx[0] -> cur regs
    if (t < 256) {
        const int hb = t >> 4, hk = (t & 15) * 8;
        const float* ph = h0 + (size_t)(bb + hb) * HID + hk;
        *(bf16x8*)(hA + SW(hb, hk * 2)) =
            cvt8(*(const float4*)ph, *(const float4*)(ph + 4));
    }
    uint2 gpr, gpz, gpn, gqr, gqz, gqn;   // ping-pong gx regs (bf16x4 each)
    {
        const __bf16* p = gx + gxoff;     // s = 0
        gpr = *(const uint2*)(p);
        gpz = *(const uint2*)(p + HID);
        gpn = *(const uint2*)(p + 2 * HID);
    }
    asm volatile("s_waitcnt lgkmcnt(0)" ::: "memory");
    __builtin_amdgcn_s_barrier();

    auto STEP = [&](int s, unsigned char* hR, unsigned char* hW,
                    uint2& gcr, uint2& gcz, uint2& gcn,
                    uint2& gnr, uint2& gnz, uint2& gnn) {
        // 1. prefetch gx[s+1] (consumed next step; never waited on here)
        {
            int sp = s + 1; if (sp > SEQ - 1) sp = SEQ - 1;
            const __bf16* p = gx + (size_t)sp * BATCH * G3 + gxoff;
            gnr = *(const uint2*)(p);
            gnz = *(const uint2*)(p + HID);
            gnn = *(const uint2*)(p + 2 * HID);
        }

        // 2. h B-fragments from LDS
        bf16x8 Bh[4];
        #pragma unroll
        for (int kt = 0; kt < 4; ++kt)
            Bh[kt] = *(const bf16x8*)(hR + SW(col, kt * 64 + lr * 16));

        // 3. MFMA: 12 per wave (gh only), acc init = b_hh
        f32x4 ar = vbr, az = vbz, anh = vbnh;
        #pragma unroll
        for (int kt = 0; kt < 4; ++kt) {
            ar  = mfma16(aW[0][kt], Bh[kt], ar);
            az  = mfma16(aW[1][kt], Bh[kt], az);
            anh = mfma16(aW[2][kt], Bh[kt], anh);
        }

        // 4. gate math; gx (loaded >=1 step ago) unpacked from regs
        float xr[4] = { bflo(gcr.x), bfhi(gcr.x), bflo(gcr.y), bfhi(gcr.y) };
        float xz[4] = { bflo(gcz.x), bfhi(gcz.x), bflo(gcz.y), bfhi(gcz.y) };
        float xn[4] = { bflo(gcn.x), bfhi(gcn.x), bflo(gcn.y), bfhi(gcn.y) };
        f32x4 hnew;
        #pragma unroll
        for (int q = 0; q < 4; ++q) {
            float r = sigm(ar[q] + xr[q]);
            float z = sigm(az[q] + xz[q]);
            float n = tanh_fast(xn[q] + r * anh[q]);
            hnew[q] = n + z * (hold[q] - n);
        }
        hold = hnew;
        *(bf16x4*)(hW + SW(col, (w * 16 + lr * 4) * 2)) = cvt4(*(float4*)&hnew);
        float4 o; o.x = hnew[0]; o.y = hnew[1]; o.z = hnew[2]; o.w = hnew[3];
        *(float4*)(out + ((size_t)s * BATCH + bb + col) * HID + w * 16 + lr * 4) = o;

        // 5. single barrier: LDS visibility only; vmcnt flows across
        asm volatile("s_waitcnt lgkmcnt(0)" ::: "memory");
        __builtin_amdgcn_s_barrier();
    };

    for (int s0 = 0; s0 < SEQ; s0 += 2) {
        STEP(s0,     hA, hB, gpr, gpz, gpn, gqr, gqz, gqn);
        STEP(s0 + 1, hB, hA, gqr, gqz, gqn, gpr, gpz, gpn);
    }
}

// ===========================================================================
// FALLBACK PATH (round-7 kernels, ~439 us) -- used when ws_size is small
// ===========================================================================
__global__ void fold_kernel(const float* __restrict__ lin_W,
                            const float* __restrict__ lin_b,
                            const float* __restrict__ W_ih,
                            const float* __restrict__ b_ih,
                            float* __restrict__ Wc,
                            float* __restrict__ bcA) {
    const int g = blockIdx.x;
    const int d = threadIdx.x;
    float acc = 0.f;
    for (int e = 0; e < HID; ++e) acc += W_ih[g * HID + e] * lin_W[e * HID + d];
    Wc[g * HID + d] = acc;
    if (d == 0) {
        float b = 0.f;
        for (int e = 0; e < HID; ++e) b += W_ih[g * HID + e] * lin_b[e];
        bcA[g] = b + b_ih[g];
    }
}

__global__ __launch_bounds__(512, 2)
void gru_scan_mfma(const float* __restrict__ X,
                   const float* __restrict__ h0,
                   const float* __restrict__ W_hh,
                   const float* __restrict__ b_hh,
                   const float* __restrict__ Wc,
                   const float* __restrict__ bcA,
                   float* __restrict__ out) {
    const int t   = threadIdx.x;
    const int w   = t >> 6;
    const int l   = t & 63;
    const int col = l & 15;
    const int lr  = l >> 4;
    const int bb  = blockIdx.x * NB;

    __shared__ __align__(16) unsigned char lds[16384];
    unsigned char* hA = lds;
    unsigned char* hB = lds + 4096;
    unsigned char* xA = lds + 8192;
    unsigned char* xB = lds + 12288;

    auto SW = [](int b, int off) { return b * 256 + (off ^ ((b & 7) << 4)); };

    bf16x8 aW[3][4], aC[3][4];
    #pragma unroll
    for (int g3 = 0; g3 < 3; ++g3)
        #pragma unroll
        for (int kt = 0; kt < 4; ++kt) {
            const int row = g3 * HID + w * 16 + col;
            const float* pw = W_hh + row * HID + kt * 32 + lr * 8;
            const float* pc = Wc   + row * HID + kt * 32 + lr * 8;
            aW[g3][kt] = cvt8(*(const float4*)pw, *(const float4*)(pw + 4));
            aC[g3][kt] = cvt8(*(const float4*)pc, *(const float4*)(pc + 4));
        }
    #pragma unroll
    for (int g3 = 0; g3 < 3; ++g3)
        #pragma unroll
        for (int kt = 0; kt < 4; ++kt) {
            asm volatile("" : "+v"(aW[g3][kt]));
            asm volatile("" : "+v"(aC[g3][kt]));
        }

    f32x4 vbr, vbz, vbnx, vbnh;
    #pragma unroll
    for (int q = 0; q < 4; ++q) {
        const int g = w * 16 + lr * 4 + q;
        vbr[q]  = bcA[g] + b_hh[g];
        vbz[q]  = bcA[HID + g] + b_hh[HID + g];
        vbnx[q] = bcA[2 * HID + g];
        vbnh[q] = b_hh[2 * HID + g];
    }

    f32x4 hold = *(const f32x4*)(h0 + (size_t)(bb + col) * HID + w * 16 + lr * 4);

    const int sb = t >> 5;
    const int sk = (t & 31) * 4;

    float4 xp, xq;
    if (t < 256) {
        const int hb = t >> 4, hk = (t & 15) * 8;
        const float* ph = h0 + (size_t)(bb + hb) * HID + hk;
        *(bf16x8*)(hA + SW(hb, hk * 2)) =
            cvt8(*(const float4*)ph, *(const float4*)(ph + 4));
    }
    {
        const float* px = X + ((size_t)0 * BATCH + bb + sb) * HID + sk;
        *(bf16x4*)(xA + SW(sb, sk * 2)) = cvt4(*(const float4*)px);
        const float* p1 = X + ((size_t)1 * BATCH + bb + sb) * HID + sk;
        xp = *(const float4*)p1;
    }
    asm volatile("s_waitcnt lgkmcnt(0)" ::: "memory");
    __builtin_amdgcn_s_barrier();

    auto STEP = [&](int s, unsigned char* hR, unsigned char* hW,
                    unsigned char* xR, unsigned char* xW,
                    float4& xc, float4& xn) {
        *(bf16x4*)(xW + SW(sb, sk * 2)) = cvt4(xc);
        {
            int sp = s + 2; if (sp > SEQ - 1) sp = SEQ - 1;
            const float* px = X + ((size_t)sp * BATCH + bb + sb) * HID + sk;
            xn = *(const float4*)px;
        }
        bf16x8 Bh[4], Bx[4];
        #pragma unroll
        for (int kt = 0; kt < 4; ++kt) {
            Bh[kt] = *(const bf16x8*)(hR + SW(col, kt * 64 + lr * 16));
            Bx[kt] = *(const bf16x8*)(xR + SW(col, kt * 64 + lr * 16));
        }
        f32x4 ar = vbr, az = vbz, anh = vbnh, anx = vbnx;
        #pragma unroll
        for (int kt = 0; kt < 4; ++kt) {
            ar  = mfma16(aW[0][kt], Bh[kt], ar);
            ar  = mfma16(aC[0][kt], Bx[kt], ar);
            az  = mfma16(aW[1][kt], Bh[kt], az);
            az  = mfma16(aC[1][kt], Bx[kt], az);
            anh = mfma16(aW[2][kt], Bh[kt], anh);
            anx = mfma16(aC[2][kt], Bx[kt], anx);
        }
        f32x4 hnew;
        #pragma unroll
        for (int q = 0; q < 4; ++q) {
            float r = sigm(ar[q]);
            float z = sigm(az[q]);
            float n = tanh_fast(anx[q] + r * anh[q]);
            hnew[q] = n + z * (hold[q] - n);
        }
        hold = hnew;
        *(bf16x4*)(hW + SW(col, (w * 16 + lr * 4) * 2)) = cvt4(*(float4*)&hnew);
        float4 o; o.x = hnew[0]; o.y = hnew[1]; o.z = hnew[2]; o.w = hnew[3];
        *(float4*)(out + ((size_t)s * BATCH + bb + col) * HID + w * 16 + lr * 4) = o;
        asm volatile("s_waitcnt lgkmcnt(0)" ::: "memory");
        __builtin_amdgcn_s_barrier();
    };

    for (int s0 = 0; s0 < SEQ; s0 += 2) {
        STEP(s0,     hA, hB, xA, xB, xp, xq);
        STEP(s0 + 1, hB, hA, xB, xA, xq, xp);
    }
}

// ---------------------------------------------------------------------------
extern "C" void kernel_launch(void* const* d_in, const int* in_sizes, int n_in,
                              void* d_out, int out_size, void* d_ws, size_t ws_size,
                              hipStream_t stream) {
    const float* X     = (const float*)d_in[0];
    const float* h0    = (const float*)d_in[1];
    const float* lin_W = (const float*)d_in[2];
    const float* lin_b = (const float*)d_in[3];
    const float* W_ih  = (const float*)d_in[4];
    const float* W_hh  = (const float*)d_in[5];
    const float* b_ih  = (const float*)d_in[6];
    const float* b_hh  = (const float*)d_in[7];
    float* out = (float*)d_out;

    const size_t GX_BYTES   = (size_t)SEQ * BATCH * G3 * 2;  // 100663296
    const size_t WCBF_BYTES = (size_t)G3 * HID * 2;          // 98304
    const size_t BCA_BYTES  = (size_t)G3 * 4;                // 1536

    if (ws_size >= GX_BYTES + WCBF_BYTES + BCA_BYTES) {
        // FAST PATH: precompute gx via full-chip GEMM, then light scan
        __bf16* gxp  = (__bf16*)d_ws;
        __bf16* Wcbf = (__bf16*)((char*)d_ws + GX_BYTES);
        float*  bcA  = (float*)((char*)d_ws + GX_BYTES + WCBF_BYTES);

        fold_bf16_kernel<<<G3, HID, 0, stream>>>(lin_W, lin_b, W_ih, b_ih, Wcbf, bcA);
        gemm_gx_kernel<<<(SEQ * BATCH) / 128, 512, 0, stream>>>(X, Wcbf, bcA, gxp);
        gru_scan_light<<<NBLK, 512, 0, stream>>>(h0, W_hh, b_hh, gxp, out);
    } else {
        // FALLBACK: fused round-7 path (~439 us)
        float* Wc  = (float*)d_ws;
        float* bcA = Wc + G3 * HID;
        fold_kernel<<<G3, HID, 0, stream>>>(lin_W, lin_b, W_ih, b_ih, Wc, bcA);
        gru_scan_mfma<<<NBLK, 512, 0, stream>>>(X, h0, W_hh, b_hh, Wc, bcA, out);
    }
}

// Round 9
// 454.246 us; speedup vs baseline: 1.1302x; 1.1302x over previous
//
#include <hip/hip_runtime.h>
#include <math.h>

#define HID 128
#define G3  384
#define BATCH 256
#define SEQ 512
#define NB 16            // batch tile per scan block
#define NBLK (BATCH/NB)  // 16 scan blocks

typedef __bf16 bf16x8 __attribute__((ext_vector_type(8)));
typedef __bf16 bf16x4 __attribute__((ext_vector_type(4)));
typedef float  f32x4  __attribute__((ext_vector_type(4)));

#define LOG2E 1.44269504088896f

__device__ __forceinline__ float sigm(float x) {
    return __builtin_amdgcn_rcpf(1.f + __builtin_amdgcn_exp2f(-LOG2E * x));
}
__device__ __forceinline__ float tanh_fast(float x) {
    float e = __builtin_amdgcn_exp2f(-2.f * LOG2E * x);
    return __builtin_amdgcn_rcpf(1.f + e) * 2.f - 1.f;
}
__device__ __forceinline__ f32x4 mfma16(bf16x8 a, bf16x8 b, f32x4 c) {
    return __builtin_amdgcn_mfma_f32_16x16x32_bf16(a, b, c, 0, 0, 0);
}
__device__ __forceinline__ bf16x8 cvt8(float4 a, float4 b) {
    bf16x8 f;
    f[0] = (__bf16)a.x; f[1] = (__bf16)a.y; f[2] = (__bf16)a.z; f[3] = (__bf16)a.w;
    f[4] = (__bf16)b.x; f[5] = (__bf16)b.y; f[6] = (__bf16)b.z; f[7] = (__bf16)b.w;
    return f;
}
__device__ __forceinline__ bf16x4 cvt4(float4 a) {
    bf16x4 f;
    f[0] = (__bf16)a.x; f[1] = (__bf16)a.y; f[2] = (__bf16)a.z; f[3] = (__bf16)a.w;
    return f;
}
__device__ __forceinline__ float bflo(unsigned u) { return __uint_as_float(u << 16); }
__device__ __forceinline__ float bfhi(unsigned u) { return __uint_as_float(u & 0xffff0000u); }

// ===========================================================================
// FAST PATH
// ===========================================================================

// ---- fold: Wcbf = bf16(W_ih @ lin_W), bcA = W_ih @ lin_b + b_ih ----------
__global__ void fold_bf16_kernel(const float* __restrict__ lin_W,
                                 const float* __restrict__ lin_b,
                                 const float* __restrict__ W_ih,
                                 const float* __restrict__ b_ih,
                                 __bf16* __restrict__ Wcbf,
                                 float* __restrict__ bcA) {
    const int g = blockIdx.x;
    const int d = threadIdx.x;
    float acc = 0.f;
    #pragma unroll 16
    for (int e = 0; e < HID; ++e) acc += W_ih[g * HID + e] * lin_W[e * HID + d];
    Wcbf[g * HID + d] = (__bf16)acc;
    if (d == 0) {
        float b = 0.f;
        for (int e = 0; e < HID; ++e) b += W_ih[g * HID + e] * lin_b[e];
        bcA[g] = b + b_ih[g];
    }
}

// ---- gx GEMM: register-resident A (6 g-tiles/wave), streamed X -----------
// 1024 blocks x 256 thr (4 waves). Block owns 128 m-rows (8 m-tiles).
// Wave w owns g-tiles w*6 .. w*6+5. X double-buffered in registers.
#define GEMM_TILE(MT, CUR, NXT)                                               \
  {                                                                           \
    int mtn_ = (MT) + 1; if (mtn_ > 7) mtn_ = 7;                              \
    const float* pxn_ = X + (size_t)(m0 + mtn_ * 16 + col) * HID + lr * 8;    \
    _Pragma("unroll")                                                         \
    for (int kt = 0; kt < 4; ++kt) {                                          \
        NXT[2 * kt]     = *(const float4*)(pxn_ + kt * 32);                   \
        NXT[2 * kt + 1] = *(const float4*)(pxn_ + kt * 32 + 4);               \
    }                                                                         \
    bf16x8 Bx_[4];                                                            \
    _Pragma("unroll")                                                         \
    for (int kt = 0; kt < 4; ++kt) Bx_[kt] = cvt8(CUR[2 * kt], CUR[2 * kt + 1]); \
    const int m_ = m0 + (MT) * 16 + col;                                      \
    _Pragma("unroll")                                                         \
    for (int j = 0; j < 6; ++j) {                                             \
        f32x4 acc_ = vb[j];                                                   \
        acc_ = mfma16(A[j][0], Bx_[0], acc_);                                 \
        acc_ = mfma16(A[j][1], Bx_[1], acc_);                                 \
        acc_ = mfma16(A[j][2], Bx_[2], acc_);                                 \
        acc_ = mfma16(A[j][3], Bx_[3], acc_);                                 \
        float4 o_; o_.x = acc_[0]; o_.y = acc_[1]; o_.z = acc_[2]; o_.w = acc_[3]; \
        *(bf16x4*)(gx + (size_t)m_ * G3 + (w * 6 + j) * 16 + lr * 4) = cvt4(o_); \
    }                                                                         \
  }

__global__ __launch_bounds__(256, 2)
void gemm_gx2(const float* __restrict__ X,
              const __bf16* __restrict__ Wcbf,
              const float* __restrict__ bcA,
              __bf16* __restrict__ gx) {
    const int t   = threadIdx.x;
    const int w   = t >> 6;     // 0..3: owns g-tiles w*6 .. w*6+5
    const int l   = t & 63;
    const int col = l & 15;
    const int lr  = l >> 4;
    const int m0  = blockIdx.x * 128;

    // resident A fragments (96 VGPRs)
    bf16x8 A[6][4];
    #pragma unroll
    for (int j = 0; j < 6; ++j)
        #pragma unroll
        for (int kt = 0; kt < 4; ++kt)
            A[j][kt] = *(const bf16x8*)(Wcbf +
                (size_t)((w * 6 + j) * 16 + col) * HID + kt * 32 + lr * 8);
    #pragma unroll
    for (int j = 0; j < 6; ++j)
        #pragma unroll
        for (int kt = 0; kt < 4; ++kt)
            asm volatile("" : "+v"(A[j][kt]));

    f32x4 vb[6];
    #pragma unroll
    for (int j = 0; j < 6; ++j)
        vb[j] = *(const f32x4*)(bcA + (w * 6 + j) * 16 + lr * 4);

    float4 xe[8], xo[8];
    {
        const float* px = X + (size_t)(m0 + col) * HID + lr * 8;
        #pragma unroll
        for (int kt = 0; kt < 4; ++kt) {
            xe[2 * kt]     = *(const float4*)(px + kt * 32);
            xe[2 * kt + 1] = *(const float4*)(px + kt * 32 + 4);
        }
    }
    for (int mt = 0; mt < 8; mt += 2) {
        GEMM_TILE(mt,     xe, xo);
        GEMM_TILE(mt + 1, xo, xe);
    }
}

// ---- light scan with asm gx prefetch + counted vmcnt ---------------------
#define SCAN_STEP(S, HR, HW, CR, CZ, CN, NR, NZ, NN)                          \
  {                                                                           \
    /* 1. issue gx[S+1] prefetch via raw asm (cannot be sunk) */              \
    int sp_ = (S) + 1; if (sp_ > SEQ - 1) sp_ = SEQ - 1;                      \
    const __bf16* p_ = gx + (size_t)sp_ * (BATCH * G3) + gxoff;               \
    asm volatile("global_load_dwordx2 %0, %3, off\n\t"                        \
                 "global_load_dwordx2 %1, %3, off offset:256\n\t"             \
                 "global_load_dwordx2 %2, %3, off offset:512"                 \
                 : "=&v"(NR), "=&v"(NZ), "=&v"(NN) : "v"(p_) : "memory");     \
    /* 2. h B-fragments from LDS */                                           \
    bf16x8 Bh_[4];                                                            \
    _Pragma("unroll")                                                         \
    for (int kt = 0; kt < 4; ++kt)                                            \
        Bh_[kt] = *(const bf16x8*)((HR) + SW(col, kt * 64 + lr * 16));        \
    /* 3. MFMA: 12 per wave, acc init = b_hh */                               \
    f32x4 ar_ = vbr, az_ = vbz, anh_ = vbnh;                                  \
    _Pragma("unroll")                                                         \
    for (int kt = 0; kt < 4; ++kt) {                                          \
        ar_  = mfma16(aW[0][kt], Bh_[kt], ar_);                               \
        az_  = mfma16(aW[1][kt], Bh_[kt], az_);                               \
        anh_ = mfma16(aW[2][kt], Bh_[kt], anh_);                              \
    }                                                                         \
    /* 4. counted wait: gx[S] (issued a full step ago) landed.               \
          per-step vmem = 3 loads + 1 out store -> newest 4 may fly */        \
    asm volatile("s_waitcnt vmcnt(4)" ::: "memory");                          \
    __builtin_amdgcn_sched_barrier(0);                                        \
    /* 5. gate math (fp32, registers) */                                      \
    float xr_[4] = { bflo(CR.x), bfhi(CR.x), bflo(CR.y), bfhi(CR.y) };        \
    float xz_[4] = { bflo(CZ.x), bfhi(CZ.x), bflo(CZ.y), bfhi(CZ.y) };        \
    float xn_[4] = { bflo(CN.x), bfhi(CN.x), bflo(CN.y), bfhi(CN.y) };        \
    f32x4 hnew_;                                                              \
    _Pragma("unroll")                                                         \
    for (int q = 0; q < 4; ++q) {                                             \
        float r_ = sigm(ar_[q] + xr_[q]);                                     \
        float z_ = sigm(az_[q] + xz_[q]);                                     \
        float n_ = tanh_fast(xn_[q] + r_ * anh_[q]);                          \
        hnew_[q] = n_ + z_ * (hold[q] - n_);                                  \
    }                                                                         \
    hold = hnew_;                                                             \
    *(bf16x4*)((HW) + SW(col, (w * 16 + lr * 4) * 2)) = cvt4(*(float4*)&hnew_); \
    float4 o_; o_.x = hnew_[0]; o_.y = hnew_[1]; o_.z = hnew_[2]; o_.w = hnew_[3]; \
    *(float4*)(out + ((size_t)(S) * BATCH + bb + col) * HID + w * 16 + lr * 4) = o_; \
    /* 6. single barrier: LDS visibility only; vmcnt flows across */          \
    asm volatile("s_waitcnt lgkmcnt(0)" ::: "memory");                        \
    __builtin_amdgcn_s_barrier();                                             \
  }

__global__ __launch_bounds__(512, 2)
void gru_scan_light2(const float* __restrict__ h0,
                     const float* __restrict__ W_hh,
                     const float* __restrict__ b_hh,
                     const __bf16* __restrict__ gx,
                     float* __restrict__ out) {
    const int t   = threadIdx.x;
    const int w   = t >> 6;     // 0..7: row tile
    const int l   = t & 63;
    const int col = l & 15;
    const int lr  = l >> 4;
    const int bb  = blockIdx.x * NB;

    __shared__ __align__(16) unsigned char lds[8192];
    unsigned char* hA = lds;
    unsigned char* hB = lds + 4096;

    auto SW = [](int b, int off) { return b * 256 + (off ^ ((b & 7) << 4)); };

    // resident W_hh A-fragments (48 VGPRs), pinned
    bf16x8 aW[3][4];
    #pragma unroll
    for (int g3 = 0; g3 < 3; ++g3)
        #pragma unroll
        for (int kt = 0; kt < 4; ++kt) {
            const int row = g3 * HID + w * 16 + col;
            const float* pw = W_hh + row * HID + kt * 32 + lr * 8;
            aW[g3][kt] = cvt8(*(const float4*)pw, *(const float4*)(pw + 4));
        }
    #pragma unroll
    for (int g3 = 0; g3 < 3; ++g3)
        #pragma unroll
        for (int kt = 0; kt < 4; ++kt)
            asm volatile("" : "+v"(aW[g3][kt]));

    f32x4 vbr, vbz, vbnh;
    #pragma unroll
    for (int q = 0; q < 4; ++q) {
        const int g = w * 16 + lr * 4 + q;
        vbr[q]  = b_hh[g];
        vbz[q]  = b_hh[HID + g];
        vbnh[q] = b_hh[2 * HID + g];
    }

    f32x4 hold = *(const f32x4*)(h0 + (size_t)(bb + col) * HID + w * 16 + lr * 4);

    // Force all compiler vmem loads to complete in the prologue so the loop's
    // vmcnt counting sees ONLY our asm loads + the out store.
    asm volatile("" :: "v"(hold), "v"(vbr), "v"(vbz), "v"(vbnh));

    const size_t gxoff = (size_t)(bb + col) * G3 + w * 16 + lr * 4;

    if (t < 256) {
        const int hb = t >> 4, hk = (t & 15) * 8;
        const float* ph = h0 + (size_t)(bb + hb) * HID + hk;
        *(bf16x8*)(hA + SW(hb, hk * 2)) =
            cvt8(*(const float4*)ph, *(const float4*)(ph + 4));
    }

    // prime: gx[0] via asm (3 loads) + 1 dummy load (uniform vmcnt(4) math)
    uint2 gcr, gcz, gcn, gnr, gnz, gnn, gdm;
    {
        const __bf16* p_ = gx + gxoff;
        asm volatile("global_load_dwordx2 %0, %3, off\n\t"
                     "global_load_dwordx2 %1, %3, off offset:256\n\t"
                     "global_load_dwordx2 %2, %3, off offset:512"
                     : "=&v"(gcr), "=&v"(gcz), "=&v"(gcn) : "v"(p_) : "memory");
        asm volatile("global_load_dwordx2 %0, %1, off"
                     : "=&v"(gdm) : "v"(p_) : "memory");
    }
    asm volatile("s_waitcnt lgkmcnt(0)" ::: "memory");
    __builtin_amdgcn_s_barrier();

    for (int s0 = 0; s0 < SEQ; s0 += 2) {
        SCAN_STEP(s0,     hA, hB, gcr, gcz, gcn, gnr, gnz, gnn);
        SCAN_STEP(s0 + 1, hB, hA, gnr, gnz, gnn, gcr, gcz, gcn);
    }
    // keep dummy's dest registers live past its (long-completed) load
    asm volatile("" :: "v"(gdm));
}

// ===========================================================================
// FALLBACK PATH (round-7 kernels, ~439 us) -- used when ws_size is small
// ===========================================================================
__global__ void fold_kernel(const float* __restrict__ lin_W,
                            const float* __restrict__ lin_b,
                            const float* __restrict__ W_ih,
                            const float* __restrict__ b_ih,
                            float* __restrict__ Wc,
                            float* __restrict__ bcA) {
    const int g = blockIdx.x;
    const int d = threadIdx.x;
    float acc = 0.f;
    for (int e = 0; e < HID; ++e) acc += W_ih[g * HID + e] * lin_W[e * HID + d];
    Wc[g * HID + d] = acc;
    if (d == 0) {
        float b = 0.f;
        for (int e = 0; e < HID; ++e) b += W_ih[g * HID + e] * lin_b[e];
        bcA[g] = b + b_ih[g];
    }
}

__global__ __launch_bounds__(512, 2)
void gru_scan_mfma(const float* __restrict__ X,
                   const float* __restrict__ h0,
                   const float* __restrict__ W_hh,
                   const float* __restrict__ b_hh,
                   const float* __restrict__ Wc,
                   const float* __restrict__ bcA,
                   float* __restrict__ out) {
    const int t   = threadIdx.x;
    const int w   = t >> 6;
    const int l   = t & 63;
    const int col = l & 15;
    const int lr  = l >> 4;
    const int bb  = blockIdx.x * NB;

    __shared__ __align__(16) unsigned char lds[16384];
    unsigned char* hA = lds;
    unsigned char* hB = lds + 4096;
    unsigned char* xA = lds + 8192;
    unsigned char* xB = lds + 12288;

    auto SW = [](int b, int off) { return b * 256 + (off ^ ((b & 7) << 4)); };

    bf16x8 aW[3][4], aC[3][4];
    #pragma unroll
    for (int g3 = 0; g3 < 3; ++g3)
        #pragma unroll
        for (int kt = 0; kt < 4; ++kt) {
            const int row = g3 * HID + w * 16 + col;
            const float* pw = W_hh + row * HID + kt * 32 + lr * 8;
            const float* pc = Wc   + row * HID + kt * 32 + lr * 8;
            aW[g3][kt] = cvt8(*(const float4*)pw, *(const float4*)(pw + 4));
            aC[g3][kt] = cvt8(*(const float4*)pc, *(const float4*)(pc + 4));
        }
    #pragma unroll
    for (int g3 = 0; g3 < 3; ++g3)
        #pragma unroll
        for (int kt = 0; kt < 4; ++kt) {
            asm volatile("" : "+v"(aW[g3][kt]));
            asm volatile("" : "+v"(aC[g3][kt]));
        }

    f32x4 vbr, vbz, vbnx, vbnh;
    #pragma unroll
    for (int q = 0; q < 4; ++q) {
        const int g = w * 16 + lr * 4 + q;
        vbr[q]  = bcA[g] + b_hh[g];
        vbz[q]  = bcA[HID + g] + b_hh[HID + g];
        vbnx[q] = bcA[2 * HID + g];
        vbnh[q] = b_hh[2 * HID + g];
    }

    f32x4 hold = *(const f32x4*)(h0 + (size_t)(bb + col) * HID + w * 16 + lr * 4);

    const int sb = t >> 5;
    const int sk = (t & 31) * 4;

    float4 xp, xq;
    if (t < 256) {
        const int hb = t >> 4, hk = (t & 15) * 8;
        const float* ph = h0 + (size_t)(bb + hb) * HID + hk;
        *(bf16x8*)(hA + SW(hb, hk * 2)) =
            cvt8(*(const float4*)ph, *(const float4*)(ph + 4));
    }
    {
        const float* px = X + ((size_t)0 * BATCH + bb + sb) * HID + sk;
        *(bf16x4*)(xA + SW(sb, sk * 2)) = cvt4(*(const float4*)px);
        const float* p1 = X + ((size_t)1 * BATCH + bb + sb) * HID + sk;
        xp = *(const float4*)p1;
    }
    asm volatile("s_waitcnt lgkmcnt(0)" ::: "memory");
    __builtin_amdgcn_s_barrier();

    auto STEP = [&](int s, unsigned char* hR, unsigned char* hW,
                    unsigned char* xR, unsigned char* xW,
                    float4& xc, float4& xn) {
        *(bf16x4*)(xW + SW(sb, sk * 2)) = cvt4(xc);
        {
            int sp = s + 2; if (sp > SEQ - 1) sp = SEQ - 1;
            const float* px = X + ((size_t)sp * BATCH + bb + sb) * HID + sk;
            xn = *(const float4*)px;
        }
        bf16x8 Bh[4], Bx[4];
        #pragma unroll
        for (int kt = 0; kt < 4; ++kt) {
            Bh[kt] = *(const bf16x8*)(hR + SW(col, kt * 64 + lr * 16));
            Bx[kt] = *(const bf16x8*)(xR + SW(col, kt * 64 + lr * 16));
        }
        f32x4 ar = vbr, az = vbz, anh = vbnh, anx = vbnx;
        #pragma unroll
        for (int kt = 0; kt < 4; ++kt) {
            ar  = mfma16(aW[0][kt], Bh[kt], ar);
            ar  = mfma16(aC[0][kt], Bx[kt], ar);
            az  = mfma16(aW[1][kt], Bh[kt], az);
            az  = mfma16(aC[1][kt], Bx[kt], az);
            anh = mfma16(aW[2][kt], Bh[kt], anh);
            anx = mfma16(aC[2][kt], Bx[kt], anx);
        }
        f32x4 hnew;
        #pragma unroll
        for (int q = 0; q < 4; ++q) {
            float r = sigm(ar[q]);
            float z = sigm(az[q]);
            float n = tanh_fast(anx[q] + r * anh[q]);
            hnew[q] = n + z * (hold[q] - n);
        }
        hold = hnew;
        *(bf16x4*)(hW + SW(col, (w * 16 + lr * 4) * 2)) = cvt4(*(float4*)&hnew);
        float4 o; o.x = hnew[0]; o.y = hnew[1]; o.z = hnew[2]; o.w = hnew[3];
        *(float4*)(out + ((size_t)s * BATCH + bb + col) * HID + w * 16 + lr * 4) = o;
        asm volatile("s_waitcnt lgkmcnt(0)" ::: "memory");
        __builtin_amdgcn_s_barrier();
    };

    for (int s0 = 0; s0 < SEQ; s0 += 2) {
        STEP(s0,     hA, hB, xA, xB, xp, xq);
        STEP(s0 + 1, hB, hA, xB, xA, xq, xp);
    }
}

// ---------------------------------------------------------------------------
extern "C" void kernel_launch(void* const* d_in, const int* in_sizes, int n_in,
                              void* d_out, int out_size, void* d_ws, size_t ws_size,
                              hipStream_t stream) {
    const float* X     = (const float*)d_in[0];
    const float* h0    = (const float*)d_in[1];
    const float* lin_W = (const float*)d_in[2];
    const float* lin_b = (const float*)d_in[3];
    const float* W_ih  = (const float*)d_in[4];
    const float* W_hh  = (const float*)d_in[5];
    const float* b_ih  = (const float*)d_in[6];
    const float* b_hh  = (const float*)d_in[7];
    float* out = (float*)d_out;

    const size_t GX_BYTES   = (size_t)SEQ * BATCH * G3 * 2;  // 100663296
    const size_t WCBF_BYTES = (size_t)G3 * HID * 2;          // 98304
    const size_t BCA_BYTES  = (size_t)G3 * 4;                // 1536

    if (ws_size >= GX_BYTES + WCBF_BYTES + BCA_BYTES) {
        __bf16* gxp  = (__bf16*)d_ws;
        __bf16* Wcbf = (__bf16*)((char*)d_ws + GX_BYTES);
        float*  bcA  = (float*)((char*)d_ws + GX_BYTES + WCBF_BYTES);

        fold_bf16_kernel<<<G3, HID, 0, stream>>>(lin_W, lin_b, W_ih, b_ih, Wcbf, bcA);
        gemm_gx2<<<(SEQ * BATCH) / 128, 256, 0, stream>>>(X, Wcbf, bcA, gxp);
        gru_scan_light2<<<NBLK, 512, 0, stream>>>(h0, W_hh, b_hh, gxp, out);
    } else {
        float* Wc  = (float*)d_ws;
        float* bcA = Wc + G3 * HID;
        fold_kernel<<<G3, HID, 0, stream>>>(lin_W, lin_b, W_ih, b_ih, Wc, bcA);
        gru_scan_mfma<<<NBLK, 512, 0, stream>>>(X, h0, W_hh, b_hh, Wc, bcA, out);
    }
}